// Round 12
// baseline (57.496 us; speedup 1.0000x reference)
//
#include <hip/hip_runtime.h>

#define T_STEPS 32
#define BATCH   65536
#define IN_DIM  27
#define H_DIM   10
#define H2_DIM  5

typedef _Float16 f16_t;
typedef _Float16 f16x4 __attribute__((ext_vector_type(4)));
typedef __fp16   h16x2 __attribute__((ext_vector_type(2)));   // cvt_pkrtz native type
typedef float    f32x4 __attribute__((ext_vector_type(4)));

__device__ __forceinline__ float fast_exp2(float v) { return __builtin_amdgcn_exp2f(v); }
__device__ __forceinline__ float fast_rcp(float v)  { return __builtin_amdgcn_rcpf(v); }
__device__ __forceinline__ float fast_sigmoid(float v) {
    return fast_rcp(1.f + fast_exp2(v * -1.4426950408889634f));
}
__device__ __forceinline__ float fast_tanh(float v) {
    return 1.f - 2.f * fast_rcp(1.f + fast_exp2(v * 2.8853900817779268f));
}

// unaligned-safe 16B global load (word rows are 108 B -> only 4B alignment)
__device__ __forceinline__ f32x4 load4u(const float* p) {
    f32x4 v; __builtin_memcpy(&v, p, 16); return v;
}

// packed f32x4 -> f16x4 via 2x v_cvt_pkrtz_f16_f32 (bit-reinterpret __fp16 -> _Float16)
__device__ __forceinline__ f16x4 cvt4(f32x4 v) {
    union { h16x2 h2[2]; f16x4 h4; } u;
    u.h2[0] = __builtin_amdgcn_cvt_pkrtz(v[0], v[1]);
    u.h2[1] = __builtin_amdgcn_cvt_pkrtz(v[2], v[3]);
    return u.h4;
}

// ---------------------------------------------------------------------------
// Fully-fused MFMA LSTM, software-pipelined (R10 -> R12):
// xacc(t+1) = bias + X(t+1)@Wih^T (8 MFMAs, h-INDEPENDENT) is computed while
// step t's h-chain runs; the h-dependent chain per step collapses to ONE MFMA
// per gate type: acc = mfma(ah, bfh, xacc). x loads are depth-2 (issue x(t+3)
// during step t). All pipeline buffers statically indexed via 2-step unroll.
// Layout (R9/R10-validated, 16x16x16 f16):
//   A: row=lane&15, k=(lane>>4)*4+i; B: col=lane&15 same k;
//   C: lane(kg,bn) reg -> (row kg*4+reg, col bn).
// Gate dim padded 40->64: nt = gate TYPE, so each lane holds all 4 types of
// (elem kg*4+reg, unit bn) -> LSTM update needs zero shuffles.
// h feedback via per-wave LDS table (C-layout write, A-fragment read).
// x K-split: ks0 = cols 0..15; ks1 = cols 11..26 with B rows j<5 zeroed.
// ---------------------------------------------------------------------------
__global__
__attribute__((amdgpu_flat_work_group_size(256, 256), amdgpu_waves_per_eu(4, 4)))
void lstm_fused_mfma(
    const float* __restrict__ word,   // [T, B, IN]
    const float* __restrict__ W_ih,   // [40, 27]
    const float* __restrict__ W_hh,   // [40, 10]
    const float* __restrict__ b_ih,   // [40]
    const float* __restrict__ b_hh,   // [40]
    const float* __restrict__ W_fc,   // [5, 10]
    const float* __restrict__ b_fc,   // [5]
    const float* __restrict__ W_out,  // [1, 5]
    const float* __restrict__ b_out,  // [1]
    float* __restrict__ out)          // [B]
{
    __shared__ __align__(16) f16_t s_h[4][16 * 20];   // per-wave h table, 2560 B

    const int tid  = threadIdx.x;
    const int lane = tid & 63;
    const int w    = tid >> 6;
    const int bn   = lane & 15;       // fragment col (gate unit) / A row (elem)
    const int kg   = lane >> 4;       // fragment k-group
    const int e0   = blockIdx.x * 64 + w * 16;   // wave's 16 elements

    // ---- resident weight fragments (loaded once; gates padded 40->64) ----
    const bool gok = (bn < H_DIM);
    f16x4 bfx0[4], bfx1[4], bfh[4];
    f32x4 biasv[4];
#pragma unroll
    for (int nt = 0; nt < 4; ++nt) {  // nt = gate type: 0=i 1=f 2=g 3=o
        const int g = nt * H_DIM + bn;
        const float bv = gok ? (b_ih[g] + b_hh[g]) : 0.f;
        biasv[nt] = (f32x4){bv, bv, bv, bv};
#pragma unroll
        for (int i = 0; i < 4; ++i) {
            const int k = kg * 4 + i;
            bfx0[nt][i] = (f16_t)(gok ? W_ih[g * IN_DIM + k] : 0.f);                  // cols 0..15
            bfx1[nt][i] = (f16_t)((gok && k >= 5) ? W_ih[g * IN_DIM + 11 + k] : 0.f); // cols 16..26
            bfh[nt][i]  = (f16_t)((gok && k < H_DIM) ? W_hh[g * H_DIM + k] : 0.f);    // units 0..9
        }
    }

    f16_t* tb = &s_h[w][0];
    {   // zero exactly the slots the A_h reads touch (h0 = 0)
        f16x4 z = {(f16_t)0.f, (f16_t)0.f, (f16_t)0.f, (f16_t)0.f};
        *(f16x4*)(tb + bn * 20 + kg * 4) = z;
    }

    float c[4];
#pragma unroll
    for (int r = 0; r < 4; ++r) c[r] = 0.f;

    // x addressing: A row = elem bn; ks0 at col kg*4, ks1 at col 11+kg*4
    const float* xbase = word + (size_t)(e0 + bn) * IN_DIM;
    const size_t tstep = (size_t)BATCH * IN_DIM;
    const int c0 = kg * 4, c1 = 11 + kg * 4;

    // ---- prologue: x(0) -> xaccA; x(1) in regs; x(2) in flight ----
    f32x4 xaccA[4], xaccB[4];
    f32x4 xaC, xbC, xaN, xbN;
    {
        f32x4 x0a = load4u(xbase + c0);
        f32x4 x0b = load4u(xbase + c1);
        xaC = load4u(xbase + tstep + c0);        // x(1)
        xbC = load4u(xbase + tstep + c1);
        xaN = load4u(xbase + 2 * tstep + c0);    // x(2)
        xbN = load4u(xbase + 2 * tstep + c1);
        const f16x4 a0 = cvt4(x0a), a1 = cvt4(x0b);
#pragma unroll
        for (int nt = 0; nt < 4; ++nt)
            xaccA[nt] = __builtin_amdgcn_mfma_f32_16x16x16f16(
                a1, bfx1[nt],
                __builtin_amdgcn_mfma_f32_16x16x16f16(a0, bfx0[nt], biasv[nt], 0, 0, 0),
                0, 0, 0);
    }

    // step body: consumes XC (this step's h-independent gates), builds XN from
    // (xaC,xbC) = x(t+1), rotates x regs from the in-flight (xaN,xbN) = x(t+2),
    // and issues the load of x(t+3).
#define STEP_BODY(XC, XN, T)                                                     \
    {                                                                            \
        /* issue x(T+3) load (depth-2 in flight) */                              \
        const int tn = ((T) + 3 < T_STEPS) ? (T) + 3 : (T_STEPS - 1);            \
        const float* xr = xbase + (size_t)tn * tstep;                            \
        f32x4 fa = load4u(xr + c0);                                              \
        f32x4 fb = load4u(xr + c1);                                              \
        /* h-independent: xacc(T+1) from x(T+1) regs (8 MFMAs, pure ILP) */      \
        const f16x4 a0 = cvt4(xaC), a1 = cvt4(xbC);                              \
        _Pragma("unroll")                                                        \
        for (int nt = 0; nt < 4; ++nt)                                           \
            XN[nt] = __builtin_amdgcn_mfma_f32_16x16x16f16(                      \
                a1, bfx1[nt],                                                    \
                __builtin_amdgcn_mfma_f32_16x16x16f16(a0, bfx0[nt], biasv[nt],   \
                                                      0, 0, 0), 0, 0, 0);        \
        /* h-dependent chain: ds_read -> 1 MFMA/type -> trans -> ds_write */     \
        const f16x4 ah = *(const f16x4*)(tb + bn * 20 + kg * 4);                 \
        f32x4 acc[4];                                                            \
        _Pragma("unroll")                                                        \
        for (int nt = 0; nt < 4; ++nt)                                           \
            acc[nt] = __builtin_amdgcn_mfma_f32_16x16x16f16(ah, bfh[nt],         \
                                                            XC[nt], 0, 0, 0);   \
        _Pragma("unroll")                                                        \
        for (int reg = 0; reg < 4; ++reg) {                                      \
            const float iv = fast_sigmoid(acc[0][reg]);                          \
            const float fv = fast_sigmoid(acc[1][reg]);                          \
            const float gv = fast_tanh   (acc[2][reg]);                          \
            const float ov = fast_sigmoid(acc[3][reg]);                          \
            const float cn = fmaf(fv, c[reg], iv * gv);                          \
            c[reg] = fmaxf(cn, 0.f);                                             \
            const float hv = ov * fast_tanh(c[reg]);                             \
            tb[(kg * 4 + reg) * 20 + bn] = (f16_t)hv;                            \
        }                                                                        \
        /* rotate x regs */                                                      \
        xaC = xaN; xbC = xbN; xaN = fa; xbN = fb;                                \
    }

#pragma unroll 1
    for (int t = 0; t < T_STEPS; t += 2) {
        STEP_BODY(xaccA, xaccB, t)
        STEP_BODY(xaccB, xaccA, t + 1)
    }
#undef STEP_BODY

    // ---- head on lanes 0..15 (one per elem) ----
    if (lane < 16) {
        float hv[H_DIM];
#pragma unroll
        for (int u = 0; u < H_DIM; ++u) hv[u] = (float)tb[lane * 20 + u];
        float accv = b_out[0];
#pragma unroll
        for (int p = 0; p < H2_DIM; ++p) {
            float y = b_fc[p];
#pragma unroll
            for (int m = 0; m < H_DIM; ++m) y = fmaf(W_fc[p * H_DIM + m], hv[m], y);
            y = fmaxf(y, 0.f);
            accv = fmaf(W_out[p], y, accv);
        }
        out[e0 + lane] = fast_sigmoid(accv);
    }
}

extern "C" void kernel_launch(void* const* d_in, const int* in_sizes, int n_in,
                              void* d_out, int out_size, void* d_ws, size_t ws_size,
                              hipStream_t stream) {
    const float* word  = (const float*)d_in[0];
    const float* W_ih  = (const float*)d_in[1];
    const float* W_hh  = (const float*)d_in[2];
    const float* b_ih  = (const float*)d_in[3];
    const float* b_hh  = (const float*)d_in[4];
    const float* W_fc  = (const float*)d_in[5];
    const float* b_fc  = (const float*)d_in[6];
    const float* W_out = (const float*)d_in[7];
    const float* b_out = (const float*)d_in[8];
    float* out = (float*)d_out;

    // 16 elems/wave, 4 waves/block -> 64 elems/block -> 1024 blocks (4/CU)
    lstm_fused_mfma<<<BATCH / 64, 256, 0, stream>>>(
        word, W_ih, W_hh, b_ih, b_hh, W_fc, b_fc, W_out, b_out, out);
}

// Round 13
// 55.759 us; speedup vs baseline: 1.0312x; 1.0312x over previous
//
#include <hip/hip_runtime.h>

#define T_STEPS 32
#define BATCH   65536
#define IN_DIM  27
#define H_DIM   10
#define H2_DIM  5

typedef _Float16 f16_t;
typedef _Float16 f16x4 __attribute__((ext_vector_type(4)));
typedef float    f32x4 __attribute__((ext_vector_type(4)));

__device__ __forceinline__ float fast_exp2(float v) { return __builtin_amdgcn_exp2f(v); }
__device__ __forceinline__ float fast_rcp(float v)  { return __builtin_amdgcn_rcpf(v); }
__device__ __forceinline__ float fast_sigmoid(float v) {
    return fast_rcp(1.f + fast_exp2(v * -1.4426950408889634f));
}
__device__ __forceinline__ float fast_tanh(float v) {
    return 1.f - 2.f * fast_rcp(1.f + fast_exp2(v * 2.8853900817779268f));
}

// unaligned-safe 16B global load (word rows are 108 B -> only 4B alignment)
__device__ __forceinline__ f32x4 load4u(const float* p) {
    f32x4 v; __builtin_memcpy(&v, p, 16); return v;
}

// ---------------------------------------------------------------------------
// Fully-fused MFMA LSTM (R10 body, proven 54.8us) + occupancy bump:
// waves_per_eu(5,5) caps VGPR at 102 -> 5 blocks/CU = 5 waves/SIMD (was 4).
// R12's dep-chain restructure was null (-5%) -> kernel is NOT chain-limited;
// cycle model says ~35% of the step period is latency bubbles that extra TLP
// should fill (HBM pipe 2700 cyc vs measured 4110 cyc per SIMD-step).
// Layout (R9/R10-validated, 16x16x16 f16):
//   A: row=lane&15, k=(lane>>4)*4+i; B: col=lane&15 same k;
//   C: lane(kg,bn) reg -> (row kg*4+reg, col bn).
// Gate dim padded 40->64: nt = gate TYPE -> each lane holds all 4 types of
// (elem kg*4+reg, unit bn): update needs zero shuffles.
// h feedback via per-wave LDS table (C-layout write, A-fragment read).
// x K-split: ks0 = cols 0..15; ks1 = cols 11..26 with B rows j<5 zeroed.
// ---------------------------------------------------------------------------
__global__
__attribute__((amdgpu_flat_work_group_size(256, 256), amdgpu_waves_per_eu(5, 5)))
void lstm_fused_mfma(
    const float* __restrict__ word,   // [T, B, IN]
    const float* __restrict__ W_ih,   // [40, 27]
    const float* __restrict__ W_hh,   // [40, 10]
    const float* __restrict__ b_ih,   // [40]
    const float* __restrict__ b_hh,   // [40]
    const float* __restrict__ W_fc,   // [5, 10]
    const float* __restrict__ b_fc,   // [5]
    const float* __restrict__ W_out,  // [1, 5]
    const float* __restrict__ b_out,  // [1]
    float* __restrict__ out)          // [B]
{
    __shared__ __align__(16) f16_t s_h[4][16 * 20];   // per-wave h table, 2560 B

    const int tid  = threadIdx.x;
    const int lane = tid & 63;
    const int w    = tid >> 6;
    const int bn   = lane & 15;       // fragment col (gate unit) / A row (elem)
    const int kg   = lane >> 4;       // fragment k-group
    const int e0   = blockIdx.x * 64 + w * 16;   // wave's 16 elements

    // ---- resident weight fragments (loaded once; gates padded 40->64) ----
    const bool gok = (bn < H_DIM);
    f16x4 bfx0[4], bfx1[4], bfh[4];
    float bias[4];
#pragma unroll
    for (int nt = 0; nt < 4; ++nt) {  // nt = gate type: 0=i 1=f 2=g 3=o
        const int g = nt * H_DIM + bn;
        bias[nt] = gok ? (b_ih[g] + b_hh[g]) : 0.f;
#pragma unroll
        for (int i = 0; i < 4; ++i) {
            const int k = kg * 4 + i;
            bfx0[nt][i] = (f16_t)(gok ? W_ih[g * IN_DIM + k] : 0.f);                  // cols 0..15
            bfx1[nt][i] = (f16_t)((gok && k >= 5) ? W_ih[g * IN_DIM + 11 + k] : 0.f); // cols 16..26
            bfh[nt][i]  = (f16_t)((gok && k < H_DIM) ? W_hh[g * H_DIM + k] : 0.f);    // units 0..9
        }
    }

    f16_t* tb = &s_h[w][0];
    {   // zero exactly the slots the A_h reads touch (h0 = 0)
        f16x4 z = {(f16_t)0.f, (f16_t)0.f, (f16_t)0.f, (f16_t)0.f};
        *(f16x4*)(tb + bn * 20 + kg * 4) = z;
    }

    float c[4];
#pragma unroll
    for (int r = 0; r < 4; ++r) c[r] = 0.f;

    // x addressing: A row = elem bn; ks0 at col kg*4, ks1 at col 11+kg*4
    const float* xbase = word + (size_t)(e0 + bn) * IN_DIM;
    const size_t tstep = (size_t)BATCH * IN_DIM;
    const int c0 = kg * 4, c1 = 11 + kg * 4;

    f32x4 xa = load4u(xbase + c0);
    f32x4 xb = load4u(xbase + c1);

    for (int t = 0; t < T_STEPS; ++t) {
        // ---- prefetch next step's x (clamped re-read on last iter: L1-hot) ----
        const float* xr = xbase + (size_t)((t + 1 < T_STEPS) ? t + 1 : t) * tstep;
        f32x4 na = load4u(xr + c0);
        f32x4 nb = load4u(xr + c1);

        // ---- previous h as A-fragment: A[row=bn=elem][k=kg*4+i=unit] ----
        const f16x4 ah = *(const f16x4*)(tb + bn * 20 + kg * 4);

        // ---- current x -> f16 A-fragments ----
        f16x4 ax0, ax1;
#pragma unroll
        for (int i = 0; i < 4; ++i) { ax0[i] = (f16_t)xa[i]; ax1[i] = (f16_t)xb[i]; }

        // ---- gates = bias + X@Wih^T + H@Whh^T  (12 MFMA, weights resident) ----
        f32x4 acc[4];
#pragma unroll
        for (int nt = 0; nt < 4; ++nt) {
            f32x4 a = {bias[nt], bias[nt], bias[nt], bias[nt]};
            a = __builtin_amdgcn_mfma_f32_16x16x16f16(ax0, bfx0[nt], a, 0, 0, 0);
            a = __builtin_amdgcn_mfma_f32_16x16x16f16(ax1, bfx1[nt], a, 0, 0, 0);
            a = __builtin_amdgcn_mfma_f32_16x16x16f16(ah,  bfh[nt],  a, 0, 0, 0);
            acc[nt] = a;
        }

        // ---- update: lane owns (elem kg*4+reg, unit bn); all 4 types local ----
#pragma unroll
        for (int reg = 0; reg < 4; ++reg) {
            const float iv = fast_sigmoid(acc[0][reg]);
            const float fv = fast_sigmoid(acc[1][reg]);
            const float gv = fast_tanh   (acc[2][reg]);
            const float ov = fast_sigmoid(acc[3][reg]);
            const float cn = fmaf(fv, c[reg], iv * gv);
            c[reg] = fmaxf(cn, 0.f);                  // relu'd carry
            const float hv = ov * fast_tanh(c[reg]);  // >=0: relu(h) == h
            tb[(kg * 4 + reg) * 20 + bn] = (f16_t)hv; // C-layout -> table
        }

        xa = na; xb = nb;
    }

    // ---- head on lanes 0..15 (one per elem) ----
    if (lane < 16) {
        float hv[H_DIM];
#pragma unroll
        for (int u = 0; u < H_DIM; ++u) hv[u] = (float)tb[lane * 20 + u];
        float accv = b_out[0];
#pragma unroll
        for (int p = 0; p < H2_DIM; ++p) {
            float y = b_fc[p];
#pragma unroll
            for (int m = 0; m < H_DIM; ++m) y = fmaf(W_fc[p * H_DIM + m], hv[m], y);
            y = fmaxf(y, 0.f);
            accv = fmaf(W_out[p], y, accv);
        }
        out[e0 + lane] = fast_sigmoid(accv);
    }
}

extern "C" void kernel_launch(void* const* d_in, const int* in_sizes, int n_in,
                              void* d_out, int out_size, void* d_ws, size_t ws_size,
                              hipStream_t stream) {
    const float* word  = (const float*)d_in[0];
    const float* W_ih  = (const float*)d_in[1];
    const float* W_hh  = (const float*)d_in[2];
    const float* b_ih  = (const float*)d_in[3];
    const float* b_hh  = (const float*)d_in[4];
    const float* W_fc  = (const float*)d_in[5];
    const float* b_fc  = (const float*)d_in[6];
    const float* W_out = (const float*)d_in[7];
    const float* b_out = (const float*)d_in[8];
    float* out = (float*)d_out;

    // 16 elems/wave, 4 waves/block -> 64 elems/block -> 1024 blocks (5/CU now)
    lstm_fused_mfma<<<BATCH / 64, 256, 0, stream>>>(
        word, W_ih, W_hh, b_ih, b_hh, W_fc, b_fc, W_out, b_out, out);
}